// Round 1
// baseline (457.575 us; speedup 1.0000x reference)
//
#include <hip/hip_runtime.h>
#include <hip/hip_bf16.h>

// TextualContrastiveLoss: B=4096, D=1024, NUM_CLASSES=100, T=0.5
//   z = l2norm(emb); reps = [z_i; z_j] (8192x1024)
//   sim = reps @ reps^T; e = exp(sim/T) with diag excluded
//   loss = mean_n( log(sum_m e) - log(sum_{m: lab match} e) )
//
// Strategy: fp32 normalize -> bf16 reps in ws; fused 128x128-tile MFMA GEMM
// (m97 structure: global_load_lds width16, BK=64, 16x16x32 bf16) with
// exp/mask/row-sum epilogue + atomics; tiny finalize reduction.

#define BHALF 4096
#define N2 8192
#define DK 1024
#define TILE 128
#define BK 64

typedef __attribute__((ext_vector_type(4))) float f32x4;
typedef __attribute__((ext_vector_type(8))) short bf16x8;
typedef unsigned short u16;

// exp(s/0.5) = exp2(s * 2*log2(e))
#define EXP_SCALE 2.8853900817779268f

static __device__ inline u16 f2bf_rne(float x) {
    unsigned u = __builtin_bit_cast(unsigned, x);
    unsigned r = (u + 0x7fff + ((u >> 16) & 1)) >> 16;
    return (u16)r;
}

__global__ __launch_bounds__(256) void normalize_kernel(
    const float* __restrict__ emb_i, const float* __restrict__ emb_j,
    u16* __restrict__ reps) {
    int r = blockIdx.x;           // 0..8191
    int t = threadIdx.x;          // 0..255, one float4 each (1024 floats/row)
    const float* src = (r < BHALF) ? (emb_i + (size_t)r * DK)
                                   : (emb_j + (size_t)(r - BHALF) * DK);
    float4 v = ((const float4*)src)[t];
    float s = v.x * v.x + v.y * v.y + v.z * v.z + v.w * v.w;
#pragma unroll
    for (int m = 1; m <= 32; m <<= 1) s += __shfl_xor(s, m, 64);
    __shared__ float red[4];
    if ((t & 63) == 0) red[t >> 6] = s;
    __syncthreads();
    float tot = red[0] + red[1] + red[2] + red[3];
    float scale = 1.0f / fmaxf(sqrtf(tot), 1e-12f);
    ushort4 o;
    o.x = f2bf_rne(v.x * scale);
    o.y = f2bf_rne(v.y * scale);
    o.z = f2bf_rne(v.z * scale);
    o.w = f2bf_rne(v.w * scale);
    ((ushort4*)(reps + (size_t)r * DK))[t] = o;
}

__global__ __launch_bounds__(256) void zero_kernel(float* __restrict__ p, int n) {
    int i = blockIdx.x * 256 + threadIdx.x;
    if (i < n) p[i] = 0.0f;
}

__global__ __launch_bounds__(256) void gemm_loss_kernel(
    const u16* __restrict__ reps, const int* __restrict__ labels,
    float* __restrict__ nom, float* __restrict__ den) {
    // LDS: A 128x64 bf16 (16KB) + B 128x64 (16KB) + labels (1KB)
    __shared__ __align__(16) u16 A_s[TILE * BK];
    __shared__ __align__(16) u16 B_s[TILE * BK];
    __shared__ int labR_s[TILE];
    __shared__ int labC_s[TILE];

    // 8-row supertile swizzle for L2 locality: bi fastest within bands of 8
    int g = blockIdx.x;
    int group = g >> 9;            // /512
    int rem = g & 511;
    int bi = (group << 3) + (rem & 7);
    int bj = rem >> 3;
    int rowBase = bi * TILE;
    int colBase = bj * TILE;

    int tid = threadIdx.x;
    int w = tid >> 6;              // wave 0..3 -> 2x2 of 64x64 subtiles
    int lane = tid & 63;
    int wm = w >> 1, wn = w & 1;
    int quad = lane >> 4;
    int l15 = lane & 15;

    if (tid < 128) labR_s[tid] = labels[(rowBase + tid) & (BHALF - 1)];
    else           labC_s[tid - 128] = labels[(colBase + tid - 128) & (BHALF - 1)];

    f32x4 acc[4][4];
#pragma unroll
    for (int i = 0; i < 4; ++i)
#pragma unroll
        for (int j = 0; j < 4; ++j)
            acc[i][j] = (f32x4){0.f, 0.f, 0.f, 0.f};

    // staging: each lane loads 16B (8 bf16); chunk = 8 rows of 64 = 1KB
    int srow = lane >> 3;          // 0..7
    int scol = (lane & 7) * 8;     // element col offset

    for (int kt = 0; kt < DK / BK; ++kt) {
        int k0 = kt * BK;
#pragma unroll
        for (int t = 0; t < 4; ++t) {
            int chunk = t * 4 + w;         // 0..15
            int r = chunk * 8 + srow;      // 0..127
            const u16* gpA = reps + (size_t)(rowBase + r) * DK + k0 + scol;
            const u16* gpB = reps + (size_t)(colBase + r) * DK + k0 + scol;
            __builtin_amdgcn_global_load_lds(
                (const __attribute__((address_space(1))) void*)gpA,
                (__attribute__((address_space(3))) void*)&A_s[chunk * 512], 16, 0, 0);
            __builtin_amdgcn_global_load_lds(
                (const __attribute__((address_space(1))) void*)gpB,
                (__attribute__((address_space(3))) void*)&B_s[chunk * 512], 16, 0, 0);
        }
        __syncthreads();   // drains vmcnt (global_load_lds) + joins
#pragma unroll
        for (int ks = 0; ks < 2; ++ks) {
            int koff = ks * 32 + quad * 8;
            bf16x8 aF[4], bF[4];
#pragma unroll
            for (int i = 0; i < 4; ++i)
                aF[i] = *(const bf16x8*)&A_s[(wm * 64 + i * 16 + l15) * BK + koff];
#pragma unroll
            for (int j = 0; j < 4; ++j)
                bF[j] = *(const bf16x8*)&B_s[(wn * 64 + j * 16 + l15) * BK + koff];
#pragma unroll
            for (int i = 0; i < 4; ++i)
#pragma unroll
                for (int j = 0; j < 4; ++j)
                    acc[i][j] = __builtin_amdgcn_mfma_f32_16x16x32_bf16(
                        aF[i], bF[j], acc[i][j], 0, 0, 0);
        }
        __syncthreads();   // all reads done before next stage overwrites
    }

    // Epilogue: e = exp2(sim*EXP_SCALE); diag excluded; label-match mask.
    // C/D layout (m89-verified): col = lane&15, row = quad*4 + reg.
#pragma unroll
    for (int i = 0; i < 4; ++i) {
#pragma unroll
        for (int reg = 0; reg < 4; ++reg) {
            int rloc = wm * 64 + i * 16 + quad * 4 + reg;
            int gr = rowBase + rloc;
            int labr = labR_s[rloc];
            float nomP = 0.f, denP = 0.f;
#pragma unroll
            for (int j = 0; j < 4; ++j) {
                int cloc = wn * 64 + j * 16 + l15;
                int gc = colBase + cloc;
                float e = exp2f(acc[i][j][reg] * EXP_SCALE);
                if (gr == gc) e = 0.f;
                denP += e;
                if (labC_s[cloc] == labr) nomP += e;
            }
            // reduce across the 16 column-lanes of this quad
#pragma unroll
            for (int m = 1; m <= 8; m <<= 1) {
                nomP += __shfl_xor(nomP, m, 64);
                denP += __shfl_xor(denP, m, 64);
            }
            if (l15 == 0) {
                atomicAdd(&den[gr], denP);
                atomicAdd(&nom[gr], nomP);
            }
        }
    }
}

__global__ __launch_bounds__(256) void finalize_kernel(
    const float* __restrict__ nom, const float* __restrict__ den,
    float* __restrict__ out) {
    int t = threadIdx.x;
    float s = 0.f;
    for (int r = t; r < N2; r += 256)
        s += logf(den[r]) - logf(nom[r]);   // -log(nom/den)
#pragma unroll
    for (int m = 1; m <= 32; m <<= 1) s += __shfl_xor(s, m, 64);
    __shared__ float red[4];
    if ((t & 63) == 0) red[t >> 6] = s;
    __syncthreads();
    if (t == 0) out[0] = (red[0] + red[1] + red[2] + red[3]) / (float)N2;
}

extern "C" void kernel_launch(void* const* d_in, const int* in_sizes, int n_in,
                              void* d_out, int out_size, void* d_ws, size_t ws_size,
                              hipStream_t stream) {
    const float* emb_i = (const float*)d_in[0];
    const float* emb_j = (const float*)d_in[1];
    const int* labels  = (const int*)d_in[2];
    float* out = (float*)d_out;

    char* ws = (char*)d_ws;
    u16* reps  = (u16*)ws;                                  // 8192*1024*2 = 16 MB
    float* nom = (float*)(ws + (size_t)N2 * DK * 2);        // 32 KB
    float* den = nom + N2;                                  // 32 KB

    normalize_kernel<<<N2, 256, 0, stream>>>(emb_i, emb_j, reps);
    zero_kernel<<<(2 * N2 + 255) / 256, 256, 0, stream>>>(nom, 2 * N2);
    gemm_loss_kernel<<<64 * 64, 256, 0, stream>>>(reps, labels, nom, den);
    finalize_kernel<<<1, 256, 0, stream>>>(nom, den, out);
}

// Round 2
// 426.972 us; speedup vs baseline: 1.0717x; 1.0717x over previous
//
#include <hip/hip_runtime.h>
#include <hip/hip_bf16.h>

// TextualContrastiveLoss: B=4096, D=1024, NUM_CLASSES=100, T=0.5
//   z = l2norm(emb); reps = [z_i; z_j] (8192x1024)
//   sim = reps @ reps^T; e = exp(sim/T) with diag excluded
//   loss = mean_n( log(sum_m e) - log(sum_{m: lab match} e) )
//
// R1: fused 128x128 MFMA GEMM, 353 TF — LDS 16-way bank conflicts (row
//     stride 128B = 32 banks) made ds_read dominate 6:1 over MFMA.
// R2: XOR bank swizzle: LDS col-block = global col-block ^ (row&7).
//     Compatible with global_load_lds (contiguous 1KB/wave dest); only the
//     lane->global-chunk mapping and the read-side index change.

#define BHALF 4096
#define N2 8192
#define DK 1024
#define TILE 128
#define BK 64

typedef __attribute__((ext_vector_type(4))) float f32x4;
typedef __attribute__((ext_vector_type(8))) short bf16x8;
typedef unsigned short u16;

// exp(s/0.5) = exp2(s * 2*log2(e))
#define EXP_SCALE 2.8853900817779268f

static __device__ inline u16 f2bf_rne(float x) {
    unsigned u = __builtin_bit_cast(unsigned, x);
    unsigned r = (u + 0x7fff + ((u >> 16) & 1)) >> 16;
    return (u16)r;
}

__global__ __launch_bounds__(256) void normalize_kernel(
    const float* __restrict__ emb_i, const float* __restrict__ emb_j,
    u16* __restrict__ reps) {
    int r = blockIdx.x;           // 0..8191
    int t = threadIdx.x;          // 0..255, one float4 each (1024 floats/row)
    const float* src = (r < BHALF) ? (emb_i + (size_t)r * DK)
                                   : (emb_j + (size_t)(r - BHALF) * DK);
    float4 v = ((const float4*)src)[t];
    float s = v.x * v.x + v.y * v.y + v.z * v.z + v.w * v.w;
#pragma unroll
    for (int m = 1; m <= 32; m <<= 1) s += __shfl_xor(s, m, 64);
    __shared__ float red[4];
    if ((t & 63) == 0) red[t >> 6] = s;
    __syncthreads();
    float tot = red[0] + red[1] + red[2] + red[3];
    float scale = 1.0f / fmaxf(sqrtf(tot), 1e-12f);
    ushort4 o;
    o.x = f2bf_rne(v.x * scale);
    o.y = f2bf_rne(v.y * scale);
    o.z = f2bf_rne(v.z * scale);
    o.w = f2bf_rne(v.w * scale);
    ((ushort4*)(reps + (size_t)r * DK))[t] = o;
}

__global__ __launch_bounds__(256) void zero_kernel(float* __restrict__ p, int n) {
    int i = blockIdx.x * 256 + threadIdx.x;
    if (i < n) p[i] = 0.0f;
}

__global__ __launch_bounds__(256) void gemm_loss_kernel(
    const u16* __restrict__ reps, const int* __restrict__ labels,
    float* __restrict__ nom, float* __restrict__ den) {
    // LDS: A 128x64 bf16 (16KB) + B 128x64 (16KB) + labels (1KB)
    // Layout swizzle: slot (row, cb_lds) holds global col-block
    // cb_g = cb_lds ^ (row & 7)   (col-block = 8 elements = 16 B)
    __shared__ __align__(16) u16 A_s[TILE * BK];
    __shared__ __align__(16) u16 B_s[TILE * BK];
    __shared__ int labR_s[TILE];
    __shared__ int labC_s[TILE];

    // 8-row supertile swizzle for L2 locality
    int g = blockIdx.x;
    int group = g >> 9;            // /512
    int rem = g & 511;
    int bi = (group << 3) + (rem & 7);
    int bj = rem >> 3;
    int rowBase = bi * TILE;
    int colBase = bj * TILE;

    int tid = threadIdx.x;
    int w = tid >> 6;              // wave 0..3 -> 2x2 of 64x64 subtiles
    int lane = tid & 63;
    int wm = w >> 1, wn = w & 1;
    int quad = lane >> 4;
    int l15 = lane & 15;

    if (tid < 128) labR_s[tid] = labels[(rowBase + tid) & (BHALF - 1)];
    else           labC_s[tid - 128] = labels[(colBase + tid - 128) & (BHALF - 1)];

    f32x4 acc[4][4];
#pragma unroll
    for (int i = 0; i < 4; ++i)
#pragma unroll
        for (int j = 0; j < 4; ++j)
            acc[i][j] = (f32x4){0.f, 0.f, 0.f, 0.f};

    // staging: lane l -> LDS offset chunk*1024B + l*16B = slot (l>>3, l&7).
    // To realize the swizzle, lane l fetches global col-block (l&7)^(l>>3&7).
    int srow = lane >> 3;                         // 0..7 (row within chunk)
    int scol = ((lane & 7) ^ srow) * 8;           // swizzled element col

    for (int kt = 0; kt < DK / BK; ++kt) {
        int k0 = kt * BK;
#pragma unroll
        for (int t = 0; t < 4; ++t) {
            int chunk = t * 4 + w;         // 0..15
            int r = chunk * 8 + srow;      // 0..127
            const u16* gpA = reps + (size_t)(rowBase + r) * DK + k0 + scol;
            const u16* gpB = reps + (size_t)(colBase + r) * DK + k0 + scol;
            __builtin_amdgcn_global_load_lds(
                (const __attribute__((address_space(1))) void*)gpA,
                (__attribute__((address_space(3))) void*)&A_s[chunk * 512], 16, 0, 0);
            __builtin_amdgcn_global_load_lds(
                (const __attribute__((address_space(1))) void*)gpB,
                (__attribute__((address_space(3))) void*)&B_s[chunk * 512], 16, 0, 0);
        }
        __syncthreads();   // drains vmcnt (global_load_lds) + joins
#pragma unroll
        for (int ks = 0; ks < 2; ++ks) {
            int cbg = ks * 4 + quad;       // global col-block of this frag
            bf16x8 aF[4], bF[4];
#pragma unroll
            for (int i = 0; i < 4; ++i) {
                int row = wm * 64 + i * 16 + l15;
                aF[i] = *(const bf16x8*)&A_s[row * BK + ((cbg ^ (row & 7)) << 3)];
            }
#pragma unroll
            for (int j = 0; j < 4; ++j) {
                int row = wn * 64 + j * 16 + l15;
                bF[j] = *(const bf16x8*)&B_s[row * BK + ((cbg ^ (row & 7)) << 3)];
            }
#pragma unroll
            for (int i = 0; i < 4; ++i)
#pragma unroll
                for (int j = 0; j < 4; ++j)
                    acc[i][j] = __builtin_amdgcn_mfma_f32_16x16x32_bf16(
                        aF[i], bF[j], acc[i][j], 0, 0, 0);
        }
        __syncthreads();   // all reads done before next stage overwrites
    }

    // Epilogue: e = exp2(sim*EXP_SCALE); diag excluded; label-match mask.
    // C/D layout (m89-verified): col = lane&15, row = quad*4 + reg.
#pragma unroll
    for (int i = 0; i < 4; ++i) {
#pragma unroll
        for (int reg = 0; reg < 4; ++reg) {
            int rloc = wm * 64 + i * 16 + quad * 4 + reg;
            int gr = rowBase + rloc;
            int labr = labR_s[rloc];
            float nomP = 0.f, denP = 0.f;
#pragma unroll
            for (int j = 0; j < 4; ++j) {
                int cloc = wn * 64 + j * 16 + l15;
                int gc = colBase + cloc;
                float e = exp2f(acc[i][j][reg] * EXP_SCALE);
                if (gr == gc) e = 0.f;
                denP += e;
                if (labC_s[cloc] == labr) nomP += e;
            }
            // reduce across the 16 column-lanes of this quad
#pragma unroll
            for (int m = 1; m <= 8; m <<= 1) {
                nomP += __shfl_xor(nomP, m, 64);
                denP += __shfl_xor(denP, m, 64);
            }
            if (l15 == 0) {
                atomicAdd(&den[gr], denP);
                atomicAdd(&nom[gr], nomP);
            }
        }
    }
}

__global__ __launch_bounds__(256) void finalize_kernel(
    const float* __restrict__ nom, const float* __restrict__ den,
    float* __restrict__ out) {
    int t = threadIdx.x;
    float s = 0.f;
    for (int r = t; r < N2; r += 256)
        s += logf(den[r]) - logf(nom[r]);   // -log(nom/den)
#pragma unroll
    for (int m = 1; m <= 32; m <<= 1) s += __shfl_xor(s, m, 64);
    __shared__ float red[4];
    if ((t & 63) == 0) red[t >> 6] = s;
    __syncthreads();
    if (t == 0) out[0] = (red[0] + red[1] + red[2] + red[3]) / (float)N2;
}

extern "C" void kernel_launch(void* const* d_in, const int* in_sizes, int n_in,
                              void* d_out, int out_size, void* d_ws, size_t ws_size,
                              hipStream_t stream) {
    const float* emb_i = (const float*)d_in[0];
    const float* emb_j = (const float*)d_in[1];
    const int* labels  = (const int*)d_in[2];
    float* out = (float*)d_out;

    char* ws = (char*)d_ws;
    u16* reps  = (u16*)ws;                                  // 8192*1024*2 = 16 MB
    float* nom = (float*)(ws + (size_t)N2 * DK * 2);        // 32 KB
    float* den = nom + N2;                                  // 32 KB

    normalize_kernel<<<N2, 256, 0, stream>>>(emb_i, emb_j, reps);
    zero_kernel<<<(2 * N2 + 255) / 256, 256, 0, stream>>>(nom, 2 * N2);
    gemm_loss_kernel<<<64 * 64, 256, 0, stream>>>(reps, labels, nom, den);
    finalize_kernel<<<1, 256, 0, stream>>>(nom, den, out);
}

// Round 3
// 243.676 us; speedup vs baseline: 1.8778x; 1.7522x over previous
//
#include <hip/hip_runtime.h>
#include <hip/hip_bf16.h>

// TextualContrastiveLoss: B=4096, D=1024, NUM_CLASSES=100, T=0.5
//   z = l2norm(emb); reps = [z_i; z_j] (8192x1024)
//   sim = reps @ reps^T; e = exp(sim/T) with diag excluded
//   loss = mean_n( log(sum_m e) - log(sum_{m: lab match} e) )
//
// R1: fused 128x128 MFMA GEMM, 353 TF — 16-way LDS bank conflicts.
// R2: XOR bank swizzle -> conflicts 0 but only -6%: latency-bound on
//     global_load_lds L2 misses (FETCH 525MB, 25% of staged bytes).
// R3: SYMMETRY. sim and the label mask are symmetric -> compute only the
//     2080 upper-tri tiles (vs 4096); each off-diag tile scatters its
//     masked-exp sums to BOTH row accumulators (rows of tile) and column
//     accumulators (rows of the transposed tile). Diagonal tiles: row sums
//     only, with diag zeroed. Halves every pipe's work.

#define BHALF 4096
#define N2 8192
#define DK 1024
#define TILE 128
#define BK 64
#define NTILE 64              // 8192/128
#define NBLK 2080             // 64*65/2 upper-tri tiles

typedef __attribute__((ext_vector_type(4))) float f32x4;
typedef __attribute__((ext_vector_type(8))) short bf16x8;
typedef unsigned short u16;

// exp(s/0.5) = exp2(s * 2*log2(e))
#define EXP_SCALE 2.8853900817779268f

static __device__ inline u16 f2bf_rne(float x) {
    unsigned u = __builtin_bit_cast(unsigned, x);
    unsigned r = (u + 0x7fff + ((u >> 16) & 1)) >> 16;
    return (u16)r;
}

__global__ __launch_bounds__(256) void normalize_kernel(
    const float* __restrict__ emb_i, const float* __restrict__ emb_j,
    u16* __restrict__ reps) {
    int r = blockIdx.x;           // 0..8191
    int t = threadIdx.x;          // 0..255, one float4 each (1024 floats/row)
    const float* src = (r < BHALF) ? (emb_i + (size_t)r * DK)
                                   : (emb_j + (size_t)(r - BHALF) * DK);
    float4 v = ((const float4*)src)[t];
    float s = v.x * v.x + v.y * v.y + v.z * v.z + v.w * v.w;
#pragma unroll
    for (int m = 1; m <= 32; m <<= 1) s += __shfl_xor(s, m, 64);
    __shared__ float red[4];
    if ((t & 63) == 0) red[t >> 6] = s;
    __syncthreads();
    float tot = red[0] + red[1] + red[2] + red[3];
    float scale = 1.0f / fmaxf(sqrtf(tot), 1e-12f);
    ushort4 o;
    o.x = f2bf_rne(v.x * scale);
    o.y = f2bf_rne(v.y * scale);
    o.z = f2bf_rne(v.z * scale);
    o.w = f2bf_rne(v.w * scale);
    ((ushort4*)(reps + (size_t)r * DK))[t] = o;
}

__global__ __launch_bounds__(256) void zero_kernel(float* __restrict__ p, int n,
                                                   float* __restrict__ out) {
    int i = blockIdx.x * 256 + threadIdx.x;
    if (i < n) p[i] = 0.0f;
    if (i == 0) out[0] = 0.0f;
}

__global__ __launch_bounds__(256) void gemm_loss_kernel(
    const u16* __restrict__ reps, const int* __restrict__ labels,
    float* __restrict__ nom, float* __restrict__ den) {
    // LDS: A 128x64 bf16 (16KB) + B 128x64 (16KB) + labels (1KB)
    // XOR swizzle: slot (row, cb_lds) holds global col-block cb_lds^(row&7)
    __shared__ __align__(16) u16 A_s[TILE * BK];
    __shared__ __align__(16) u16 B_s[TILE * BK];
    __shared__ int labR_s[TILE];
    __shared__ int labC_s[TILE];

    // upper-triangle decode: row-major over bi<=bj
    int rem = blockIdx.x;
    int bi = 0;
    while (rem >= NTILE - bi) { rem -= NTILE - bi; ++bi; }
    int bj = bi + rem;
    bool isDiag = (bi == bj);
    int rowBase = bi * TILE;
    int colBase = bj * TILE;

    int tid = threadIdx.x;
    int w = tid >> 6;              // wave 0..3 -> 2x2 of 64x64 subtiles
    int lane = tid & 63;
    int wm = w >> 1, wn = w & 1;
    int quad = lane >> 4;
    int l15 = lane & 15;

    if (tid < 128) labR_s[tid] = labels[(rowBase + tid) & (BHALF - 1)];
    else           labC_s[tid - 128] = labels[(colBase + tid - 128) & (BHALF - 1)];

    f32x4 acc[4][4];
#pragma unroll
    for (int i = 0; i < 4; ++i)
#pragma unroll
        for (int j = 0; j < 4; ++j)
            acc[i][j] = (f32x4){0.f, 0.f, 0.f, 0.f};

    // staging: lane l -> LDS offset chunk*1024B + l*16B = slot (l>>3, l&7);
    // lane fetches global col-block (l&7)^(l>>3) to realize the swizzle
    int srow = lane >> 3;                         // 0..7 (row within chunk)
    int scol = ((lane & 7) ^ srow) * 8;           // swizzled element col

    for (int kt = 0; kt < DK / BK; ++kt) {
        int k0 = kt * BK;
#pragma unroll
        for (int t = 0; t < 4; ++t) {
            int chunk = t * 4 + w;         // 0..15
            int r = chunk * 8 + srow;      // 0..127
            const u16* gpA = reps + (size_t)(rowBase + r) * DK + k0 + scol;
            const u16* gpB = reps + (size_t)(colBase + r) * DK + k0 + scol;
            __builtin_amdgcn_global_load_lds(
                (const __attribute__((address_space(1))) void*)gpA,
                (__attribute__((address_space(3))) void*)&A_s[chunk * 512], 16, 0, 0);
            __builtin_amdgcn_global_load_lds(
                (const __attribute__((address_space(1))) void*)gpB,
                (__attribute__((address_space(3))) void*)&B_s[chunk * 512], 16, 0, 0);
        }
        __syncthreads();   // drains vmcnt (global_load_lds) + joins
#pragma unroll
        for (int ks = 0; ks < 2; ++ks) {
            int cbg = ks * 4 + quad;       // global col-block of this frag
            bf16x8 aF[4], bF[4];
#pragma unroll
            for (int i = 0; i < 4; ++i) {
                int row = wm * 64 + i * 16 + l15;
                aF[i] = *(const bf16x8*)&A_s[row * BK + ((cbg ^ (row & 7)) << 3)];
            }
#pragma unroll
            for (int j = 0; j < 4; ++j) {
                int row = wn * 64 + j * 16 + l15;
                bF[j] = *(const bf16x8*)&B_s[row * BK + ((cbg ^ (row & 7)) << 3)];
            }
#pragma unroll
            for (int i = 0; i < 4; ++i)
#pragma unroll
                for (int j = 0; j < 4; ++j)
                    acc[i][j] = __builtin_amdgcn_mfma_f32_16x16x32_bf16(
                        aF[i], bF[j], acc[i][j], 0, 0, 0);
        }
        __syncthreads();   // all reads done before next stage overwrites
    }

    // Epilogue. C/D layout (m89-verified): col = lane&15, row = quad*4+reg.
    // exp values e(r,c); row sums always; col sums too if off-diagonal
    // (symmetric counterpart (c,r)); diag tile zeroes r==c.
    float colDen[4] = {0.f, 0.f, 0.f, 0.f};
    float colNom[4] = {0.f, 0.f, 0.f, 0.f};
#pragma unroll
    for (int i = 0; i < 4; ++i) {
#pragma unroll
        for (int reg = 0; reg < 4; ++reg) {
            int rloc = wm * 64 + i * 16 + quad * 4 + reg;
            int gr = rowBase + rloc;
            int labr = labR_s[rloc];
            float nomP = 0.f, denP = 0.f;
#pragma unroll
            for (int j = 0; j < 4; ++j) {
                int cloc = wn * 64 + j * 16 + l15;
                int gc = colBase + cloc;
                float e = exp2f(acc[i][j][reg] * EXP_SCALE);
                if (gr == gc) e = 0.f;     // only possible when isDiag
                bool match = (labC_s[cloc] == labr);
                denP += e;
                if (match) nomP += e;
                colDen[j] += e;
                if (match) colNom[j] += e;
            }
            // row sums: reduce across the 16 column-lanes of this quad
#pragma unroll
            for (int m = 1; m <= 8; m <<= 1) {
                nomP += __shfl_xor(nomP, m, 64);
                denP += __shfl_xor(denP, m, 64);
            }
            if (l15 == 0) {
                atomicAdd(&den[gr], denP);
                atomicAdd(&nom[gr], nomP);
            }
        }
    }
    if (!isDiag) {
        // col sums: per (j,l15) each lane holds its quad's 16-row partial;
        // reduce across the 4 quads, then quad 0 scatters 16 columns per j.
#pragma unroll
        for (int j = 0; j < 4; ++j) {
            float cd = colDen[j], cn = colNom[j];
            cd += __shfl_xor(cd, 16, 64); cn += __shfl_xor(cn, 16, 64);
            cd += __shfl_xor(cd, 32, 64); cn += __shfl_xor(cn, 32, 64);
            if (quad == 0) {
                int gc = colBase + wn * 64 + j * 16 + l15;
                atomicAdd(&den[gc], cd);
                atomicAdd(&nom[gc], cn);
            }
        }
    }
}

__global__ __launch_bounds__(256) void finalize_kernel(
    const float* __restrict__ nom, const float* __restrict__ den,
    float* __restrict__ out) {
    int idx = blockIdx.x * 256 + threadIdx.x;   // 64 blocks -> 16384 threads
    int t = threadIdx.x;
    float s = 0.f;
    if (idx < N2) s = logf(den[idx]) - logf(nom[idx]);   // -log(nom/den)
#pragma unroll
    for (int m = 1; m <= 32; m <<= 1) s += __shfl_xor(s, m, 64);
    __shared__ float red[4];
    if ((t & 63) == 0) red[t >> 6] = s;
    __syncthreads();
    if (t == 0)
        atomicAdd(out, (red[0] + red[1] + red[2] + red[3]) / (float)N2);
}

extern "C" void kernel_launch(void* const* d_in, const int* in_sizes, int n_in,
                              void* d_out, int out_size, void* d_ws, size_t ws_size,
                              hipStream_t stream) {
    const float* emb_i = (const float*)d_in[0];
    const float* emb_j = (const float*)d_in[1];
    const int* labels  = (const int*)d_in[2];
    float* out = (float*)d_out;

    char* ws = (char*)d_ws;
    u16* reps  = (u16*)ws;                                  // 8192*1024*2 = 16 MB
    float* nom = (float*)(ws + (size_t)N2 * DK * 2);        // 32 KB
    float* den = nom + N2;                                  // 32 KB

    normalize_kernel<<<N2, 256, 0, stream>>>(emb_i, emb_j, reps);
    zero_kernel<<<(2 * N2 + 255) / 256, 256, 0, stream>>>(nom, 2 * N2, out);
    gemm_loss_kernel<<<NBLK, 256, 0, stream>>>(reps, labels, nom, den);
    finalize_kernel<<<(N2 + 255) / 256, 256, 0, stream>>>(nom, den, out);
}